// Round 7
// baseline (511.023 us; speedup 1.0000x reference)
//
#include <hip/hip_runtime.h>
#include <hip/hip_bf16.h>

#define NB 4
#define NN 4096
#define MM 4096
#define DD 128
#define BN 32
#define BM 64
#define NCH 8   // m-chunks; grid = 128*8 = 1024 blocks, XCD = wg&7 exactly
#define OUT_ELEMS ((size_t)NB * NN * DD)

using f32x4  = __attribute__((ext_vector_type(4))) float;
using bf16x8 = __attribute__((ext_vector_type(8))) short;

__device__ __forceinline__ float fast_exp2(float x) {
  return __builtin_amdgcn_exp2f(x);   // v_exp_f32: D = 2^S0
}

__device__ __forceinline__ short f2bf(float x) {
  union { __hip_bfloat16 h; short s; } u;
  u.h = __float2bfloat16(x);
  return u.s;
}

__device__ __forceinline__ float bf2f(unsigned short s) {
  union { float f; unsigned u; } u;
  u.u = ((unsigned)s) << 16;
  return u.f;
}

__device__ __forceinline__ bf16x8 pack8(const float* __restrict__ p) {
  float4 a = *(const float4*)p;
  float4 b = *(const float4*)(p + 4);
  bf16x8 r;
  r[0] = f2bf(a.x); r[1] = f2bf(a.y); r[2] = f2bf(a.z); r[3] = f2bf(a.w);
  r[4] = f2bf(b.x); r[5] = f2bf(b.y); r[6] = f2bf(b.z); r[7] = f2bf(b.w);
  return r;
}

__global__ __launch_bounds__(256) void zero_out_kernel(float4* __restrict__ out) {
  out[(size_t)blockIdx.x * 256 + threadIdx.x] = (float4){0.f, 0.f, 0.f, 0.f};
}

__global__ __launch_bounds__(256) void cvt_bf16_kernel(const float* __restrict__ src,
                                                       unsigned short* __restrict__ dst) {
  size_t i = ((size_t)blockIdx.x * 256 + threadIdx.x) * 8;
  *(bf16x8*)(dst + i) = pack8(src + i);
}

// V[b][m][d] fp32 -> Vt[b][d][m] bf16, 64x64 tiles via LDS
__global__ __launch_bounds__(256) void transpose_v_kernel(const float* __restrict__ v,
                                                          unsigned short* __restrict__ vt) {
  __shared__ unsigned short t[64][72];
  const int b = blockIdx.z, d0 = blockIdx.y * 64, m0 = blockIdx.x * 64;
  const int r = threadIdx.x >> 2, c4 = threadIdx.x & 3;
  const float* src = v + ((size_t)b * MM + m0 + r) * DD + d0 + c4 * 16;
  for (int j = 0; j < 4; ++j) {
    float4 x = *(const float4*)(src + j * 4);
    int dl = c4 * 16 + j * 4;
    t[dl + 0][r] = (unsigned short)f2bf(x.x);
    t[dl + 1][r] = (unsigned short)f2bf(x.y);
    t[dl + 2][r] = (unsigned short)f2bf(x.z);
    t[dl + 3][r] = (unsigned short)f2bf(x.w);
  }
  __syncthreads();
  const int d = threadIdx.x >> 2, seg = threadIdx.x & 3;
  unsigned short* dst = vt + ((size_t)b * DD + d0 + d) * MM + m0 + seg * 16;
  *(bf16x8*)dst = *(bf16x8*)&t[d][seg * 16];
  *(bf16x8*)(dst + 8) = *(bf16x8*)&t[d][seg * 16 + 8];
}

// Sum NCH bf16 partial tensors -> f32 out
__global__ __launch_bounds__(256) void reduce8_kernel(const unsigned short* __restrict__ p,
                                                      float* __restrict__ out) {
  size_t i = ((size_t)blockIdx.x * 256 + threadIdx.x) * 8;
  float s[8] = {0, 0, 0, 0, 0, 0, 0, 0};
  for (int c = 0; c < NCH; ++c) {
    bf16x8 v = *(const bf16x8*)(p + (size_t)c * OUT_ELEMS + i);
    for (int j = 0; j < 8; ++j) s[j] += bf2f((unsigned short)v[j]);
  }
  float4 r0 = {s[0], s[1], s[2], s[3]}, r1 = {s[4], s[5], s[6], s[7]};
  *(float4*)(out + i) = r0;
  *(float4*)(out + i + 4) = r1;
}

// Raw barrier: LDS visibility only — global loads stay in flight (no vmcnt drain).
#define LGKM0_SBAR()                                        \
  do {                                                      \
    asm volatile("s_waitcnt lgkmcnt(0)" ::: "memory");      \
    __builtin_amdgcn_sched_barrier(0);                      \
    __builtin_amdgcn_s_barrier();                           \
  } while (0)

// Fused main kernel. grid = 128 ntiles x 8 chunks; wg = nt*8 + cid -> XCD = cid.
// 32 KB LDS -> 4 blocks/CU (100% occupancy). bf16 S-exchange.
// Rotated 2-barrier pipeline: QK(t0); B; { issueV(t); SM(t); B; loadQ(t+1); PV(t); QK(t+1); B }
template <bool WS, bool PART>
__global__ __launch_bounds__(512, 8) void attn_fused(
    const float* __restrict__ k, const float* __restrict__ q, const float* __restrict__ v,
    const unsigned short* __restrict__ kb, const unsigned short* __restrict__ qb,
    const unsigned short* __restrict__ vt, void* __restrict__ outp) {
  __shared__ alignas(8)  unsigned short s_pos[NB][8][64][4];   // 16 KB bf16 positional exchange
  __shared__ alignas(16) unsigned short Wl[NB][BN][BM];        // 16 KB, m XOR-swizzled

  const int tid = threadIdx.x;
  const int wv = tid >> 6, l = tid & 63, lr = l & 15, hg = l >> 4;
  const int wg = blockIdx.x;
  const int cid = wg & (NCH - 1);          // == XCD id
  const int n0 = (wg >> 3) * BN;
  const int it0 = cid * (MM / BM / NCH);
  const int it1 = it0 + (MM / BM / NCH);

  const int bq = wv >> 1, h = wv & 1;          // (batch, half) for QK/PV phases
  const int h_s = wv >> 2, fi_s = (wv >> 1) & 1, fj_s = wv & 1;  // softmax slot

  // K A-fragments (register-cached once): rows n0..n0+31 of batch bq, full D
  bf16x8 ka[2][4];
  for (int fi = 0; fi < 2; ++fi)
    for (int kf = 0; kf < 4; ++kf) {
      size_t koff = ((size_t)bq * NN + n0 + fi * 16 + lr) * DD + kf * 32 + hg * 8;
      if (WS) ka[fi][kf] = *(const bf16x8*)(kb + koff);
      else    ka[fi][kf] = pack8(k + koff);
    }

  f32x4 acc[2][4];
  for (int fi = 0; fi < 2; ++fi)
    for (int dj = 0; dj < 4; ++dj) acc[fi][dj] = (f32x4){0.f, 0.f, 0.f, 0.f};

  bf16x8 vf[4][2];   // V fragments, live across one barrier
  bf16x8 qf[2][4];   // Q fragments, prefetched one iteration ahead

  auto load_q = [&](int it) {
    const int m0 = it * BM;
    for (int fj = 0; fj < 2; ++fj)
      for (int kf = 0; kf < 4; ++kf) {
        size_t moff = ((size_t)bq * MM + m0 + h * 32 + fj * 16 + lr) * DD + kf * 32 + hg * 8;
        if (WS) qf[fj][kf] = *(const bf16x8*)(qb + moff);
        else    qf[fj][kf] = pack8(q + moff);
      }
  };

  auto qk_mfma = [&]() {
    f32x4 s[2][2];
    for (int fi = 0; fi < 2; ++fi)
      for (int fj = 0; fj < 2; ++fj) s[fi][fj] = (f32x4){0.f, 0.f, 0.f, 0.f};
    __builtin_amdgcn_s_setprio(1);
    for (int kf = 0; kf < 4; ++kf)
      for (int fi = 0; fi < 2; ++fi)
        for (int fj = 0; fj < 2; ++fj)
          s[fi][fj] = __builtin_amdgcn_mfma_f32_16x16x32_bf16(ka[fi][kf], qf[fj][kf],
                                                              s[fi][fj], 0, 0, 0);
    __builtin_amdgcn_s_setprio(0);
    for (int fi = 0; fi < 2; ++fi)
      for (int fj = 0; fj < 2; ++fj) {
        short4 pk;
        pk.x = f2bf(s[fi][fj][0]); pk.y = f2bf(s[fi][fj][1]);
        pk.z = f2bf(s[fi][fj][2]); pk.w = f2bf(s[fi][fj][3]);
        *(short4*)&s_pos[bq][h * 4 + fi * 2 + fj][l][0] = pk;   // b64, conflict-free
      }
  };

  auto issue_v = [&](int it) {
    const int m0 = it * BM;
    for (int dj = 0; dj < 4; ++dj)
      for (int kf = 0; kf < 2; ++kf) {
        if (WS) {
          vf[dj][kf] = *(const bf16x8*)(vt + ((size_t)bq * DD + h * 64 + dj * 16 + lr) * MM +
                                        m0 + kf * 32 + hg * 8);
        } else {
          bf16x8 t;
          for (int e = 0; e < 8; ++e)
            t[e] = f2bf(v[((size_t)bq * MM + m0 + kf * 32 + hg * 8 + e) * DD +
                          h * 64 + dj * 16 + lr]);
          vf[dj][kf] = t;
        }
      }
  };

  auto do_sm = [&]() {
    float sv[NB][4];
    for (int bb = 0; bb < NB; ++bb) {
      short4 sp = *(short4*)&s_pos[bb][wv][l][0];
      sv[bb][0] = bf2f((unsigned short)sp.x); sv[bb][1] = bf2f((unsigned short)sp.y);
      sv[bb][2] = bf2f((unsigned short)sp.z); sv[bb][3] = bf2f((unsigned short)sp.w);
    }
    const float L2E = 1.4426950408889634f;
    for (int qq = 0; qq < 4; ++qq) {
      // round 1: no max subtraction — |s| <~ 70 stays in f32 exp range
      float e0 = fast_exp2(sv[0][qq] * L2E), e1 = fast_exp2(sv[1][qq] * L2E);
      float e2 = fast_exp2(sv[2][qq] * L2E), e3 = fast_exp2(sv[3][qq] * L2E);
      float inv = __builtin_amdgcn_rcpf((e0 + e1) + (e2 + e3)) * L2E;
      // round 2: inputs in [0,1]
      float f0 = fast_exp2(e0 * inv), f1 = fast_exp2(e1 * inv);
      float f2v = fast_exp2(e2 * inv), f3 = fast_exp2(e3 * inv);
      float inv2 = __builtin_amdgcn_rcpf((f0 + f1) + (f2v + f3));
      const int n_loc = fi_s * 16 + hg * 4 + qq;          // C/D layout: row
      const int m_loc = h_s * 32 + fj_s * 16 + lr;        // C/D layout: col
      const int msw = m_loc ^ ((n_loc & 7) << 3);         // 16B-chunk XOR swizzle
      Wl[0][n_loc][msw] = (unsigned short)f2bf(f0 * inv2);
      Wl[1][n_loc][msw] = (unsigned short)f2bf(f1 * inv2);
      Wl[2][n_loc][msw] = (unsigned short)f2bf(f2v * inv2);
      Wl[3][n_loc][msw] = (unsigned short)f2bf(f3 * inv2);
    }
  };

  auto do_pv = [&]() {
    bf16x8 wf[2][2];
    for (int fi = 0; fi < 2; ++fi)
      for (int kf = 0; kf < 2; ++kf) {
        const int row = fi * 16 + lr, mo = kf * 32 + hg * 8;
        wf[fi][kf] = *(bf16x8*)&Wl[bq][row][mo ^ ((row & 7) << 3)];
      }
    __builtin_amdgcn_s_setprio(1);
    for (int kf = 0; kf < 2; ++kf)
      for (int fi = 0; fi < 2; ++fi)
        for (int dj = 0; dj < 4; ++dj)
          acc[fi][dj] = __builtin_amdgcn_mfma_f32_16x16x32_bf16(wf[fi][kf], vf[dj][kf],
                                                                acc[fi][dj], 0, 0, 0);
    __builtin_amdgcn_s_setprio(0);
  };

  // ---- rotated pipeline, 2 raw barriers per iteration ----
  load_q(it0);
  qk_mfma();
  LGKM0_SBAR();
  for (int t = it0; t < it1; ++t) {
    issue_v(t);              // V loads fly across the next barrier, land during SM
    do_sm();
    LGKM0_SBAR();
    if (t + 1 < it1) load_q(t + 1);   // Q latency hides under PV MFMAs
    do_pv();
    if (t + 1 < it1) qk_mfma();
    LGKM0_SBAR();
  }

  // ---- epilogue ----
  if (PART) {
    unsigned short* dst = (unsigned short*)outp + (size_t)cid * OUT_ELEMS;
    for (int fi = 0; fi < 2; ++fi)
      for (int dj = 0; dj < 4; ++dj)
        for (int qq = 0; qq < 4; ++qq)
          dst[((size_t)bq * NN + n0 + fi * 16 + hg * 4 + qq) * DD + h * 64 + dj * 16 + lr] =
              (unsigned short)f2bf(acc[fi][dj][qq]);
  } else {
    float* dst = (float*)outp;
    for (int fi = 0; fi < 2; ++fi)
      for (int dj = 0; dj < 4; ++dj)
        for (int qq = 0; qq < 4; ++qq)
          atomicAdd(dst + ((size_t)bq * NN + n0 + fi * 16 + hg * 4 + qq) * DD +
                        h * 64 + dj * 16 + lr,
                    acc[fi][dj][qq]);
  }
}

extern "C" void kernel_launch(void* const* d_in, const int* in_sizes, int n_in,
                              void* d_out, int out_size, void* d_ws, size_t ws_size,
                              hipStream_t stream) {
  (void)in_sizes; (void)n_in; (void)out_size;
  const float* k = (const float*)d_in[0];
  const float* q = (const float*)d_in[1];
  const float* v = (const float*)d_in[2];
  float* out = (float*)d_out;

  const size_t elems = (size_t)NB * MM * DD;                    // 2M per tensor
  const size_t need_bf = 3 * elems * sizeof(unsigned short);    // 12 MB
  const size_t need_full = need_bf + NCH * OUT_ELEMS * sizeof(unsigned short);  // 44 MB
  const bool use_ws = (d_ws != nullptr) && (ws_size >= need_bf);
  const bool use_part = (d_ws != nullptr) && (ws_size >= need_full);

  if (use_ws) {
    unsigned short* kb = (unsigned short*)d_ws;
    unsigned short* qb = kb + elems;
    unsigned short* vtp = qb + elems;
    cvt_bf16_kernel<<<elems / 8 / 256, 256, 0, stream>>>(k, kb);
    cvt_bf16_kernel<<<elems / 8 / 256, 256, 0, stream>>>(q, qb);
    transpose_v_kernel<<<dim3(MM / 64, DD / 64, NB), 256, 0, stream>>>(v, vtp);
    if (use_part) {
      unsigned short* partials = vtp + elems;
      attn_fused<true, true><<<dim3(NN / BN * NCH), 512, 0, stream>>>(k, q, v, kb, qb, vtp,
                                                                      (void*)partials);
      reduce8_kernel<<<OUT_ELEMS / 8 / 256, 256, 0, stream>>>(partials, out);
    } else {
      zero_out_kernel<<<(NB * NN * DD) / 4 / 256, 256, 0, stream>>>((float4*)out);
      attn_fused<true, false><<<dim3(NN / BN * NCH), 512, 0, stream>>>(k, q, v, kb, qb, vtp,
                                                                       (void*)out);
    }
  } else {
    zero_out_kernel<<<(NB * NN * DD) / 4 / 256, 256, 0, stream>>>((float4*)out);
    attn_fused<false, false><<<dim3(NN / BN * NCH), 512, 0, stream>>>(k, q, v, nullptr,
                                                                      nullptr, nullptr,
                                                                      (void*)out);
  }
}

// Round 8
// 165.250 us; speedup vs baseline: 3.0924x; 3.0924x over previous
//
#include <hip/hip_runtime.h>
#include <hip/hip_bf16.h>

#define NB 4
#define NN 4096
#define MM 4096
#define DD 128
#define BN 32
#define BM 64
#define NCH 4   // m-chunks; grid = 128*4 = 512 blocks, XCD-pinned
#define OUT_ELEMS ((size_t)NB * NN * DD)

using f32x4  = __attribute__((ext_vector_type(4))) float;
using bf16x8 = __attribute__((ext_vector_type(8))) short;

__device__ __forceinline__ float fast_exp2(float x) {
  return __builtin_amdgcn_exp2f(x);   // v_exp_f32: D = 2^S0
}

__device__ __forceinline__ short f2bf(float x) {
  union { __hip_bfloat16 h; short s; } u;
  u.h = __float2bfloat16(x);
  return u.s;
}

__device__ __forceinline__ bf16x8 pack8(const float* __restrict__ p) {
  float4 a = *(const float4*)p;
  float4 b = *(const float4*)(p + 4);
  bf16x8 r;
  r[0] = f2bf(a.x); r[1] = f2bf(a.y); r[2] = f2bf(a.z); r[3] = f2bf(a.w);
  r[4] = f2bf(b.x); r[5] = f2bf(b.y); r[6] = f2bf(b.z); r[7] = f2bf(b.w);
  return r;
}

__global__ __launch_bounds__(256) void zero_out_kernel(float4* __restrict__ out) {
  out[(size_t)blockIdx.x * 256 + threadIdx.x] = (float4){0.f, 0.f, 0.f, 0.f};
}

// K/Q fp32 [b][4096 rows][128] -> fragment-tiled bf16:
// dst[((b*256 + rf)*4 + kf)*512 + l*8 + e] = X[b][rf*16 + (l&15)][kf*32 + (l>>4)*8 + e]
__global__ __launch_bounds__(256) void cvt_frag_kernel(const float* __restrict__ src,
                                                       unsigned short* __restrict__ dst) {
  const int blk = blockIdx.x;          // b*256 + rf
  const int b = blk >> 8, rf = blk & 255;
  const int kf = threadIdx.x >> 6, l = threadIdx.x & 63;
  const int lr = l & 15, hg = l >> 4;
  const float* s = src + ((size_t)(b * 4096 + rf * 16 + lr) * DD + kf * 32 + hg * 8);
  bf16x8 r = pack8(s);
  *(bf16x8*)(dst + (((size_t)((b * 256 + rf) * 4 + kf)) << 9) + (l << 3)) = r;
}

// V fp32 [b][m][d] -> fragment-tiled transposed bf16:
// vt[((b*8 + djg)*128 + mt)*512 + l*8 + e] = V[b][mt*32 + (l>>4)*8 + e][djg*16 + (l&15)]
__global__ __launch_bounds__(256) void transpose_v_frag_kernel(const float* __restrict__ v,
                                                               unsigned short* __restrict__ vt) {
  __shared__ unsigned short t[64][72];   // [d_local][m_local], 144B rows (16B-mult)
  const int b = blockIdx.z, d0 = blockIdx.y * 64, m0 = blockIdx.x * 64;
  const int r = threadIdx.x >> 2, c4 = threadIdx.x & 3;
  const float* src = v + ((size_t)b * MM + m0 + r) * DD + d0 + c4 * 16;
  for (int j = 0; j < 4; ++j) {
    float4 x = *(const float4*)(src + j * 4);
    int dl = c4 * 16 + j * 4;
    t[dl + 0][r] = (unsigned short)f2bf(x.x);
    t[dl + 1][r] = (unsigned short)f2bf(x.y);
    t[dl + 2][r] = (unsigned short)f2bf(x.z);
    t[dl + 3][r] = (unsigned short)f2bf(x.w);
  }
  __syncthreads();
  const int s8 = threadIdx.x >> 5;          // 0..7 sub-tiles (16d x 32m)
  const int dfl = s8 & 3, mtl = s8 >> 2;
  const int t32 = threadIdx.x & 31;
  for (int ll = 0; ll < 2; ++ll) {
    const int l = t32 * 2 + ll;
    const int lr = l & 15, hg = l >> 4;
    bf16x8 val = *(bf16x8*)&t[dfl * 16 + lr][mtl * 32 + hg * 8];
    *(bf16x8*)(vt + (((size_t)((b * 8 + (d0 >> 4) + dfl) * 128 + (m0 >> 5) + mtl)) << 9) +
               (l << 3)) = val;
  }
}

// Sum NCH fragment-ordered f32 partials -> out[b][n][d]
// part idx: (((cid*4+bq)*256 + nf)*8 + djg)*256 + l*4 + qq
__global__ __launch_bounds__(256) void reduce4_frag_kernel(const float* __restrict__ p,
                                                           float* __restrict__ out) {
  const size_t idx = (size_t)blockIdx.x * 256 + threadIdx.x;  // 4*256*8*64 = 524288
  f32x4 r = *(const f32x4*)(p + idx * 4);
  for (int c = 1; c < NCH; ++c) {
    f32x4 a = *(const f32x4*)(p + (size_t)c * OUT_ELEMS + idx * 4);
    r[0] += a[0]; r[1] += a[1]; r[2] += a[2]; r[3] += a[3];
  }
  const int l = (int)(idx & 63);
  const int djg = (int)((idx >> 6) & 7);
  const int nf = (int)((idx >> 9) & 255);
  const int bq = (int)(idx >> 17);
  const int lr = l & 15, hg = l >> 4;
  float* o = out + ((size_t)(bq * 4096 + nf * 16 + hg * 4) * DD + djg * 16 + lr);
  o[0] = r[0]; o[DD] = r[1]; o[2 * DD] = r[2]; o[3 * DD] = r[3];
}

// Raw barrier: LDS visibility only — global loads stay in flight (no vmcnt drain).
#define LGKM0_SBAR()                                        \
  do {                                                      \
    asm volatile("s_waitcnt lgkmcnt(0)" ::: "memory");      \
    __builtin_amdgcn_sched_barrier(0);                      \
    __builtin_amdgcn_s_barrier();                           \
  } while (0)

// Fused main kernel. 1-D grid, XCD-pinned (chunk = wg&3, XCD = wg&7).
// All WS-path global loads are fragment-tiled: base + lane*16B (fully coalesced).
template <bool WS, bool PART>
__global__ __launch_bounds__(512, 4) void attn_fused(
    const float* __restrict__ k, const float* __restrict__ q, const float* __restrict__ v,
    const unsigned short* __restrict__ kbt, const unsigned short* __restrict__ qbt,
    const unsigned short* __restrict__ vtt, float* __restrict__ outp) {
  __shared__ alignas(16) float s_pos[NB][8][64][4];          // 32 KB positional exchange
  __shared__ alignas(16) unsigned short Wl[NB][BN][BM];      // 16 KB, m XOR-swizzled

  const int tid = threadIdx.x;
  const int wv = tid >> 6, l = tid & 63, lr = l & 15, hg = l >> 4;
  const int wg = blockIdx.x;
  const int cid = wg & (NCH - 1);
  const int n0 = (wg >> 2) * BN;
  const int it0 = cid * (MM / BM / NCH);
  const int it1 = it0 + (MM / BM / NCH);

  const int bq = wv >> 1, h = wv & 1;          // (batch, half) for QK/PV phases
  const int h_s = wv >> 2, fi_s = (wv >> 1) & 1, fj_s = wv & 1;  // softmax slot

  // K A-fragments (register-cached): rows n0..n0+31 of batch bq, full D
  bf16x8 ka[2][4];
  for (int fi = 0; fi < 2; ++fi)
    for (int kf = 0; kf < 4; ++kf) {
      if (WS) {
        ka[fi][kf] = *(const bf16x8*)(
            kbt + (((size_t)((bq * 256 + (n0 >> 4) + fi) * 4 + kf)) << 9) + (l << 3));
      } else {
        ka[fi][kf] = pack8(k + ((size_t)bq * NN + n0 + fi * 16 + lr) * DD + kf * 32 + hg * 8);
      }
    }

  f32x4 acc[2][4];
  for (int fi = 0; fi < 2; ++fi)
    for (int dj = 0; dj < 4; ++dj) acc[fi][dj] = (f32x4){0.f, 0.f, 0.f, 0.f};

  bf16x8 vf[4][2];   // V fragments, live across one barrier
  bf16x8 qf[2][4];   // Q fragments, loaded just before PV (latency hides under PV)

  auto load_q = [&](int it) {
    const int m0 = it * BM;
    for (int fj = 0; fj < 2; ++fj)
      for (int kf = 0; kf < 4; ++kf) {
        if (WS) {
          qf[fj][kf] = *(const bf16x8*)(
              qbt + (((size_t)((bq * 256 + (m0 >> 4) + h * 2 + fj) * 4 + kf)) << 9) + (l << 3));
        } else {
          qf[fj][kf] = pack8(q + ((size_t)bq * MM + m0 + h * 32 + fj * 16 + lr) * DD +
                             kf * 32 + hg * 8);
        }
      }
  };

  auto qk_mfma = [&]() {
    f32x4 s[2][2];
    for (int fi = 0; fi < 2; ++fi)
      for (int fj = 0; fj < 2; ++fj) s[fi][fj] = (f32x4){0.f, 0.f, 0.f, 0.f};
    __builtin_amdgcn_s_setprio(1);
    for (int kf = 0; kf < 4; ++kf)
      for (int fi = 0; fi < 2; ++fi)
        for (int fj = 0; fj < 2; ++fj)
          s[fi][fj] = __builtin_amdgcn_mfma_f32_16x16x32_bf16(ka[fi][kf], qf[fj][kf],
                                                              s[fi][fj], 0, 0, 0);
    __builtin_amdgcn_s_setprio(0);
    for (int fi = 0; fi < 2; ++fi)
      for (int fj = 0; fj < 2; ++fj)
        *(f32x4*)&s_pos[bq][h * 4 + fi * 2 + fj][l][0] = s[fi][fj];
  };

  auto issue_v = [&](int it) {
    const int m0 = it * BM;
    for (int dj = 0; dj < 4; ++dj)
      for (int kf = 0; kf < 2; ++kf) {
        if (WS) {
          vf[dj][kf] = *(const bf16x8*)(
              vtt + (((size_t)((bq * 8 + h * 4 + dj) * 128 + (m0 >> 5) + kf)) << 9) + (l << 3));
        } else {
          bf16x8 t;
          for (int e = 0; e < 8; ++e)
            t[e] = f2bf(v[((size_t)bq * MM + m0 + kf * 32 + hg * 8 + e) * DD +
                          h * 64 + dj * 16 + lr]);
          vf[dj][kf] = t;
        }
      }
  };

  auto do_sm = [&]() {
    f32x4 sv[NB];
    for (int bb = 0; bb < NB; ++bb) sv[bb] = *(f32x4*)&s_pos[bb][wv][l][0];
    const float L2E = 1.4426950408889634f;
    for (int qq = 0; qq < 4; ++qq) {
      // round 1: no max subtraction — |s| <~ 70 stays in f32 exp range
      float e0 = fast_exp2(sv[0][qq] * L2E), e1 = fast_exp2(sv[1][qq] * L2E);
      float e2 = fast_exp2(sv[2][qq] * L2E), e3 = fast_exp2(sv[3][qq] * L2E);
      float inv = __builtin_amdgcn_rcpf((e0 + e1) + (e2 + e3)) * L2E;
      // round 2: inputs in [0,1]
      float f0 = fast_exp2(e0 * inv), f1 = fast_exp2(e1 * inv);
      float f2v = fast_exp2(e2 * inv), f3 = fast_exp2(e3 * inv);
      float inv2 = __builtin_amdgcn_rcpf((f0 + f1) + (f2v + f3));
      const int n_loc = fi_s * 16 + hg * 4 + qq;          // C/D layout: row
      const int m_loc = h_s * 32 + fj_s * 16 + lr;        // C/D layout: col
      const int msw = m_loc ^ ((n_loc & 7) << 3);         // 16B-chunk XOR swizzle
      Wl[0][n_loc][msw] = (unsigned short)f2bf(f0 * inv2);
      Wl[1][n_loc][msw] = (unsigned short)f2bf(f1 * inv2);
      Wl[2][n_loc][msw] = (unsigned short)f2bf(f2v * inv2);
      Wl[3][n_loc][msw] = (unsigned short)f2bf(f3 * inv2);
    }
  };

  auto do_pv = [&]() {
    bf16x8 wf[2][2];
    for (int fi = 0; fi < 2; ++fi)
      for (int kf = 0; kf < 2; ++kf) {
        const int row = fi * 16 + lr, mo = kf * 32 + hg * 8;
        wf[fi][kf] = *(bf16x8*)&Wl[bq][row][mo ^ ((row & 7) << 3)];
      }
    __builtin_amdgcn_s_setprio(1);
    for (int kf = 0; kf < 2; ++kf)
      for (int fi = 0; fi < 2; ++fi)
        for (int dj = 0; dj < 4; ++dj)
          acc[fi][dj] = __builtin_amdgcn_mfma_f32_16x16x32_bf16(wf[fi][kf], vf[dj][kf],
                                                                acc[fi][dj], 0, 0, 0);
    __builtin_amdgcn_s_setprio(0);
  };

  // ---- rotated pipeline, 2 raw barriers per iteration ----
  load_q(it0);
  qk_mfma();
  LGKM0_SBAR();
  for (int t = it0; t < it1; ++t) {
    issue_v(t);                         // V loads fly across the barrier, land during SM
    do_sm();
    LGKM0_SBAR();
    if (t + 1 < it1) load_q(t + 1);     // Q latency hides under PV MFMAs
    do_pv();
    if (t + 1 < it1) qk_mfma();
    LGKM0_SBAR();
  }

  // ---- epilogue ----
  if (PART) {
    // fragment-ordered f32 partials, 16B/lane coalesced
    float* dst = outp + (size_t)cid * OUT_ELEMS;
    for (int fi = 0; fi < 2; ++fi)
      for (int dj = 0; dj < 4; ++dj) {
        size_t off = (((size_t)(bq * 256 + (n0 >> 4) + fi) * 8 + h * 4 + dj) << 8) + (l << 2);
        *(f32x4*)(dst + off) = acc[fi][dj];
      }
  } else {
    float* dst = outp;
    for (int fi = 0; fi < 2; ++fi)
      for (int dj = 0; dj < 4; ++dj)
        for (int qq = 0; qq < 4; ++qq)
          atomicAdd(dst + ((size_t)bq * NN + n0 + fi * 16 + hg * 4 + qq) * DD +
                        h * 64 + dj * 16 + lr,
                    acc[fi][dj][qq]);
  }
}

extern "C" void kernel_launch(void* const* d_in, const int* in_sizes, int n_in,
                              void* d_out, int out_size, void* d_ws, size_t ws_size,
                              hipStream_t stream) {
  (void)in_sizes; (void)n_in; (void)out_size;
  const float* k = (const float*)d_in[0];
  const float* q = (const float*)d_in[1];
  const float* v = (const float*)d_in[2];
  float* out = (float*)d_out;

  const size_t elems = (size_t)NB * MM * DD;                    // 2M per tensor
  const size_t need_bf = 3 * elems * sizeof(unsigned short);    // 12 MB
  const size_t need_full = need_bf + NCH * OUT_ELEMS * sizeof(float);  // ~46 MB (proven fits)
  const bool use_ws = (d_ws != nullptr) && (ws_size >= need_bf);
  const bool use_part = (d_ws != nullptr) && (ws_size >= need_full);

  if (use_ws) {
    unsigned short* kbt = (unsigned short*)d_ws;
    unsigned short* qbt = kbt + elems;
    unsigned short* vtt = qbt + elems;
    cvt_frag_kernel<<<NB * 256, 256, 0, stream>>>(k, kbt);
    cvt_frag_kernel<<<NB * 256, 256, 0, stream>>>(q, qbt);
    transpose_v_frag_kernel<<<dim3(MM / 64, DD / 64, NB), 256, 0, stream>>>(v, vtt);
    if (use_part) {
      float* partials = (float*)((char*)d_ws + need_bf);
      attn_fused<true, true><<<dim3(NN / BN * NCH), 512, 0, stream>>>(k, q, v, kbt, qbt, vtt,
                                                                      partials);
      reduce4_frag_kernel<<<2048, 256, 0, stream>>>(partials, out);
    } else {
      zero_out_kernel<<<(NB * NN * DD) / 4 / 256, 256, 0, stream>>>((float4*)out);
      attn_fused<true, false><<<dim3(NN / BN * NCH), 512, 0, stream>>>(k, q, v, kbt, qbt, vtt,
                                                                       out);
    }
  } else {
    zero_out_kernel<<<(NB * NN * DD) / 4 / 256, 256, 0, stream>>>((float4*)out);
    attn_fused<false, false><<<dim3(NN / BN * NCH), 512, 0, stream>>>(k, q, v, nullptr,
                                                                      nullptr, nullptr, out);
  }
}

// Round 9
// 81.719 us; speedup vs baseline: 6.2534x; 2.0222x over previous
//
#include <hip/hip_runtime.h>
#include <hip/hip_bf16.h>

#define NB 4
#define NN 4096
#define MM 4096
#define DD 128
#define BN 32
#define BM 64
#define NCH 4   // m-chunks; grid = 128*4 = 512 blocks, XCD-pinned
#define OUT_ELEMS ((size_t)NB * NN * DD)

using f32x4  = __attribute__((ext_vector_type(4))) float;
using bf16x8 = __attribute__((ext_vector_type(8))) short;

__device__ __forceinline__ float fast_exp2(float x) {
  return __builtin_amdgcn_exp2f(x);   // v_exp_f32: D = 2^S0
}

__device__ __forceinline__ int rfl(int x) {  // force wave-uniform -> SGPR
  return __builtin_amdgcn_readfirstlane(x);
}

__device__ __forceinline__ short f2bf(float x) {
  union { __hip_bfloat16 h; short s; } u;
  u.h = __float2bfloat16(x);
  return u.s;
}

__device__ __forceinline__ bf16x8 pack8(const float* __restrict__ p) {
  float4 a = *(const float4*)p;
  float4 b = *(const float4*)(p + 4);
  bf16x8 r;
  r[0] = f2bf(a.x); r[1] = f2bf(a.y); r[2] = f2bf(a.z); r[3] = f2bf(a.w);
  r[4] = f2bf(b.x); r[5] = f2bf(b.y); r[6] = f2bf(b.z); r[7] = f2bf(b.w);
  return r;
}

__global__ __launch_bounds__(256) void zero_out_kernel(float4* __restrict__ out) {
  out[(size_t)blockIdx.x * 256 + threadIdx.x] = (float4){0.f, 0.f, 0.f, 0.f};
}

// K/Q fp32 [b][4096 rows][128] -> fragment-tiled bf16:
// dst[((b*256 + rf)*4 + kf)*512 + l*8 + e] = X[b][rf*16 + (l&15)][kf*32 + (l>>4)*8 + e]
__global__ __launch_bounds__(256) void cvt_frag_kernel(const float* __restrict__ src,
                                                       unsigned short* __restrict__ dst) {
  const int blk = blockIdx.x;          // b*256 + rf
  const int b = blk >> 8, rf = blk & 255;
  const int kf = threadIdx.x >> 6, l = threadIdx.x & 63;
  const int lr = l & 15, hg = l >> 4;
  const float* s = src + ((size_t)(b * 4096 + rf * 16 + lr) * DD + kf * 32 + hg * 8);
  bf16x8 r = pack8(s);
  *(bf16x8*)(dst + (((size_t)((b * 256 + rf) * 4 + kf)) << 9) + (l << 3)) = r;
}

// V fp32 [b][m][d] -> fragment-tiled transposed bf16:
// vt[((b*8 + djg)*128 + mt)*512 + l*8 + e] = V[b][mt*32 + (l>>4)*8 + e][djg*16 + (l&15)]
__global__ __launch_bounds__(256) void transpose_v_frag_kernel(const float* __restrict__ v,
                                                               unsigned short* __restrict__ vt) {
  __shared__ unsigned short t[64][72];   // [d_local][m_local]
  const int b = blockIdx.z, d0 = blockIdx.y * 64, m0 = blockIdx.x * 64;
  const int r = threadIdx.x >> 2, c4 = threadIdx.x & 3;
  const float* src = v + ((size_t)b * MM + m0 + r) * DD + d0 + c4 * 16;
  for (int j = 0; j < 4; ++j) {
    float4 x = *(const float4*)(src + j * 4);
    int dl = c4 * 16 + j * 4;
    t[dl + 0][r] = (unsigned short)f2bf(x.x);
    t[dl + 1][r] = (unsigned short)f2bf(x.y);
    t[dl + 2][r] = (unsigned short)f2bf(x.z);
    t[dl + 3][r] = (unsigned short)f2bf(x.w);
  }
  __syncthreads();
  const int s8 = threadIdx.x >> 5;          // 0..7 sub-tiles (16d x 32m)
  const int dfl = s8 & 3, mtl = s8 >> 2;
  const int t32 = threadIdx.x & 31;
  for (int ll = 0; ll < 2; ++ll) {
    const int l = t32 * 2 + ll;
    const int lr = l & 15, hg = l >> 4;
    bf16x8 val = *(bf16x8*)&t[dfl * 16 + lr][mtl * 32 + hg * 8];
    *(bf16x8*)(vt + (((size_t)((b * 8 + (d0 >> 4) + dfl) * 128 + (m0 >> 5) + mtl)) << 9) +
               (l << 3)) = val;
  }
}

// Sum NCH fragment-ordered f32 partials -> out[b][n][d]
__global__ __launch_bounds__(256) void reduce4_frag_kernel(const float* __restrict__ p,
                                                           float* __restrict__ out) {
  const size_t idx = (size_t)blockIdx.x * 256 + threadIdx.x;  // 524288 total
  f32x4 r = *(const f32x4*)(p + idx * 4);
  for (int c = 1; c < NCH; ++c) {
    f32x4 a = *(const f32x4*)(p + (size_t)c * OUT_ELEMS + idx * 4);
    r[0] += a[0]; r[1] += a[1]; r[2] += a[2]; r[3] += a[3];
  }
  const int l = (int)(idx & 63);
  const int djg = (int)((idx >> 6) & 7);
  const int nf = (int)((idx >> 9) & 255);
  const int bq = (int)(idx >> 17);
  const int lr = l & 15, hg = l >> 4;
  float* o = out + ((size_t)(bq * 4096 + nf * 16 + hg * 4) * DD + djg * 16 + lr);
  o[0] = r[0]; o[DD] = r[1]; o[2 * DD] = r[2]; o[3 * DD] = r[3];
}

// Raw barrier: LDS visibility only — global loads stay in flight (no vmcnt drain).
#define LGKM0_SBAR()                                        \
  do {                                                      \
    asm volatile("s_waitcnt lgkmcnt(0)" ::: "memory");      \
    __builtin_amdgcn_sched_barrier(0);                      \
    __builtin_amdgcn_s_barrier();                           \
  } while (0)

// Fused main kernel. XCD-pinned chunks; fragment-tiled operands with SGPR base +
// lane*16B addressing (1 L2 transaction per wave-load).
template <bool WS, bool PART>
__global__ __launch_bounds__(512, 4) void attn_fused(
    const float* __restrict__ k, const float* __restrict__ q, const float* __restrict__ v,
    const unsigned short* __restrict__ kbt, const unsigned short* __restrict__ qbt,
    const unsigned short* __restrict__ vtt, float* __restrict__ outp) {
  __shared__ alignas(16) float s_pos[NB][8][64][4];          // 32 KB positional exchange
  __shared__ alignas(16) unsigned short Wl[NB][BN][BM];      // 16 KB, m XOR-swizzled

  const int tid = threadIdx.x;
  const int wv = tid >> 6, l = tid & 63, lr = l & 15, hg = l >> 4;
  const int voff = l << 3;                  // lane offset in elems (16 B)
  const int wg = blockIdx.x;
  const int cid = wg & (NCH - 1);
  const int n0 = (wg >> 2) * BN;
  const int it0 = cid * (MM / BM / NCH);
  const int it1 = it0 + (MM / BM / NCH);

  const int bq = wv >> 1, h = wv & 1;          // (batch, half) for QK/PV phases
  const int h_s = wv >> 2, fi_s = (wv >> 1) & 1, fj_s = wv & 1;  // softmax slot

  // K A-fragments (register-cached): SGPR base + voff + imm
  bf16x8 ka[2][4];
  {
    const unsigned short* kp = WS ? (kbt + rfl(((bq * 256 + (n0 >> 4)) * 4) << 9)) : nullptr;
    for (int fi = 0; fi < 2; ++fi)
      for (int kf = 0; kf < 4; ++kf) {
        if (WS) ka[fi][kf] = *(const bf16x8*)(kp + fi * 2048 + kf * 512 + voff);
        else    ka[fi][kf] = pack8(k + ((size_t)bq * NN + n0 + fi * 16 + lr) * DD +
                                   kf * 32 + hg * 8);
      }
  }

  f32x4 acc[2][4];
  for (int fi = 0; fi < 2; ++fi)
    for (int dj = 0; dj < 4; ++dj) acc[fi][dj] = (f32x4){0.f, 0.f, 0.f, 0.f};

  bf16x8 vf[4][2];   // V fragments, live across one barrier
  bf16x8 qf[2][4];   // Q fragments, loaded after PV (short L2 latency before QK)

  auto load_q = [&](int it) {
    if (WS) {
      const unsigned short* qp = qbt + rfl(((bq * 256 + it * 4 + h * 2) * 4) << 9);
      for (int fj = 0; fj < 2; ++fj)
        for (int kf = 0; kf < 4; ++kf)
          qf[fj][kf] = *(const bf16x8*)(qp + fj * 2048 + kf * 512 + voff);
    } else {
      const int m0 = it * BM;
      for (int fj = 0; fj < 2; ++fj)
        for (int kf = 0; kf < 4; ++kf)
          qf[fj][kf] = pack8(q + ((size_t)bq * MM + m0 + h * 32 + fj * 16 + lr) * DD +
                             kf * 32 + hg * 8);
    }
  };

  auto qk_mfma = [&]() {
    f32x4 s[2][2];
    for (int fi = 0; fi < 2; ++fi)
      for (int fj = 0; fj < 2; ++fj) s[fi][fj] = (f32x4){0.f, 0.f, 0.f, 0.f};
    __builtin_amdgcn_s_setprio(1);
    for (int kf = 0; kf < 4; ++kf)
      for (int fi = 0; fi < 2; ++fi)
        for (int fj = 0; fj < 2; ++fj)
          s[fi][fj] = __builtin_amdgcn_mfma_f32_16x16x32_bf16(ka[fi][kf], qf[fj][kf],
                                                              s[fi][fj], 0, 0, 0);
    __builtin_amdgcn_s_setprio(0);
    for (int fi = 0; fi < 2; ++fi)
      for (int fj = 0; fj < 2; ++fj)
        *(f32x4*)&s_pos[bq][h * 4 + fi * 2 + fj][l][0] = s[fi][fj];
  };

  auto issue_v = [&](int it) {
    if (WS) {
      const unsigned short* vp = vtt + rfl((((bq * 8 + h * 4) * 128) + it * 2) << 9);
      for (int dj = 0; dj < 4; ++dj)
        for (int kf = 0; kf < 2; ++kf)
          vf[dj][kf] = *(const bf16x8*)(vp + dj * 65536 + kf * 512 + voff);
    } else {
      const int m0 = it * BM;
      for (int dj = 0; dj < 4; ++dj)
        for (int kf = 0; kf < 2; ++kf) {
          bf16x8 t;
          for (int e = 0; e < 8; ++e)
            t[e] = f2bf(v[((size_t)bq * MM + m0 + kf * 32 + hg * 8 + e) * DD +
                          h * 64 + dj * 16 + lr]);
          vf[dj][kf] = t;
        }
    }
  };

  auto do_sm = [&]() {
    f32x4 sv[NB];
    for (int bb = 0; bb < NB; ++bb) sv[bb] = *(f32x4*)&s_pos[bb][wv][l][0];
    const float L2E = 1.4426950408889634f;
    for (int qq = 0; qq < 4; ++qq) {
      float e0 = fast_exp2(sv[0][qq] * L2E), e1 = fast_exp2(sv[1][qq] * L2E);
      float e2 = fast_exp2(sv[2][qq] * L2E), e3 = fast_exp2(sv[3][qq] * L2E);
      float inv = __builtin_amdgcn_rcpf((e0 + e1) + (e2 + e3)) * L2E;
      float f0 = fast_exp2(e0 * inv), f1 = fast_exp2(e1 * inv);
      float f2v = fast_exp2(e2 * inv), f3 = fast_exp2(e3 * inv);
      float inv2 = __builtin_amdgcn_rcpf((f0 + f1) + (f2v + f3));
      const int n_loc = fi_s * 16 + hg * 4 + qq;          // C/D layout: row
      const int m_loc = h_s * 32 + fj_s * 16 + lr;        // C/D layout: col
      const int msw = m_loc ^ ((n_loc & 7) << 3);         // 16B-chunk XOR swizzle
      Wl[0][n_loc][msw] = (unsigned short)f2bf(f0 * inv2);
      Wl[1][n_loc][msw] = (unsigned short)f2bf(f1 * inv2);
      Wl[2][n_loc][msw] = (unsigned short)f2bf(f2v * inv2);
      Wl[3][n_loc][msw] = (unsigned short)f2bf(f3 * inv2);
    }
  };

  auto do_pv = [&]() {
    bf16x8 wf[2][2];
    for (int fi = 0; fi < 2; ++fi)
      for (int kf = 0; kf < 2; ++kf) {
        const int row = fi * 16 + lr, mo = kf * 32 + hg * 8;
        wf[fi][kf] = *(bf16x8*)&Wl[bq][row][mo ^ ((row & 7) << 3)];
      }
    __builtin_amdgcn_s_setprio(1);
    for (int kf = 0; kf < 2; ++kf)
      for (int fi = 0; fi < 2; ++fi)
        for (int dj = 0; dj < 4; ++dj)
          acc[fi][dj] = __builtin_amdgcn_mfma_f32_16x16x32_bf16(wf[fi][kf], vf[dj][kf],
                                                                acc[fi][dj], 0, 0, 0);
    __builtin_amdgcn_s_setprio(0);
  };

  // ---- rotated pipeline, 2 raw barriers per iteration ----
  load_q(it0);
  qk_mfma();
  LGKM0_SBAR();
  for (int t = it0; t < it1; ++t) {
    issue_v(t);              // V loads in flight across the barrier, land before PV
    do_sm();
    LGKM0_SBAR();
    do_pv();                 // vf dies here -> load_q after keeps peak liveness <=112
    if (t + 1 < it1) {
      load_q(t + 1);
      qk_mfma();
    }
    LGKM0_SBAR();
  }

  // ---- epilogue ----
  if (PART) {
    // fragment-ordered f32 partials, 16B/lane coalesced, SGPR base
    float* dst = outp + (size_t)cid * OUT_ELEMS +
                 rfl((((bq * 256 + (n0 >> 4)) * 8 + h * 4)) << 8);
    for (int fi = 0; fi < 2; ++fi)
      for (int dj = 0; dj < 4; ++dj)
        *(f32x4*)(dst + fi * 2048 + dj * 256 + (l << 2)) = acc[fi][dj];
  } else {
    float* dst = outp;
    for (int fi = 0; fi < 2; ++fi)
      for (int dj = 0; dj < 4; ++dj)
        for (int qq = 0; qq < 4; ++qq)
          atomicAdd(dst + ((size_t)bq * NN + n0 + fi * 16 + hg * 4 + qq) * DD +
                        h * 64 + dj * 16 + lr,
                    acc[fi][dj][qq]);
  }
}

extern "C" void kernel_launch(void* const* d_in, const int* in_sizes, int n_in,
                              void* d_out, int out_size, void* d_ws, size_t ws_size,
                              hipStream_t stream) {
  (void)in_sizes; (void)n_in; (void)out_size;
  const float* k = (const float*)d_in[0];
  const float* q = (const float*)d_in[1];
  const float* v = (const float*)d_in[2];
  float* out = (float*)d_out;

  const size_t elems = (size_t)NB * MM * DD;                    // 2M per tensor
  const size_t need_bf = 3 * elems * sizeof(unsigned short);    // 12 MB
  const size_t need_full = need_bf + NCH * OUT_ELEMS * sizeof(float);  // 44 MB
  const bool use_ws = (d_ws != nullptr) && (ws_size >= need_bf);
  const bool use_part = (d_ws != nullptr) && (ws_size >= need_full);

  if (use_ws) {
    unsigned short* kbt = (unsigned short*)d_ws;
    unsigned short* qbt = kbt + elems;
    unsigned short* vtt = qbt + elems;
    cvt_frag_kernel<<<NB * 256, 256, 0, stream>>>(k, kbt);
    cvt_frag_kernel<<<NB * 256, 256, 0, stream>>>(q, qbt);
    transpose_v_frag_kernel<<<dim3(MM / 64, DD / 64, NB), 256, 0, stream>>>(v, vtt);
    if (use_part) {
      float* partials = (float*)((char*)d_ws + need_bf);
      attn_fused<true, true><<<dim3(NN / BN * NCH), 512, 0, stream>>>(k, q, v, kbt, qbt, vtt,
                                                                      partials);
      reduce4_frag_kernel<<<2048, 256, 0, stream>>>(partials, out);
    } else {
      zero_out_kernel<<<(NB * NN * DD) / 4 / 256, 256, 0, stream>>>((float4*)out);
      attn_fused<true, false><<<dim3(NN / BN * NCH), 512, 0, stream>>>(k, q, v, kbt, qbt, vtt,
                                                                       out);
    }
  } else {
    zero_out_kernel<<<(NB * NN * DD) / 4 / 256, 256, 0, stream>>>((float4*)out);
    attn_fused<false, false><<<dim3(NN / BN * NCH), 512, 0, stream>>>(k, q, v, nullptr,
                                                                      nullptr, nullptr, out);
  }
}

// Round 10
// 79.266 us; speedup vs baseline: 6.4469x; 1.0309x over previous
//
#include <hip/hip_runtime.h>
#include <hip/hip_bf16.h>

#define NB 4
#define NN 4096
#define MM 4096
#define DD 128
#define BN 32
#define BM 64
#define NCH 4   // m-chunks; grid = 128*4 = 512 blocks, XCD-pinned
#define OUT_ELEMS ((size_t)NB * NN * DD)

using f32x4  = __attribute__((ext_vector_type(4))) float;
using bf16x8 = __attribute__((ext_vector_type(8))) short;

__device__ __forceinline__ float fast_exp2(float x) {
  return __builtin_amdgcn_exp2f(x);   // v_exp_f32: D = 2^S0
}

__device__ __forceinline__ int rfl(int x) {  // force wave-uniform -> SGPR
  return __builtin_amdgcn_readfirstlane(x);
}

__device__ __forceinline__ short f2bf(float x) {
  union { __hip_bfloat16 h; short s; } u;
  u.h = __float2bfloat16(x);
  return u.s;
}

__device__ __forceinline__ float bf2f(unsigned short s) {
  union { float f; unsigned u; } u;
  u.u = ((unsigned)s) << 16;
  return u.f;
}

__device__ __forceinline__ bf16x8 pack8(const float* __restrict__ p) {
  float4 a = *(const float4*)p;
  float4 b = *(const float4*)(p + 4);
  bf16x8 r;
  r[0] = f2bf(a.x); r[1] = f2bf(a.y); r[2] = f2bf(a.z); r[3] = f2bf(a.w);
  r[4] = f2bf(b.x); r[5] = f2bf(b.y); r[6] = f2bf(b.z); r[7] = f2bf(b.w);
  return r;
}

__global__ __launch_bounds__(256) void zero_out_kernel(float4* __restrict__ out) {
  out[(size_t)blockIdx.x * 256 + threadIdx.x] = (float4){0.f, 0.f, 0.f, 0.f};
}

// K/Q fp32 [b][4096 rows][128] -> fragment-tiled bf16 (y=0: K->dst0, y=1: Q->dst1):
// dst[((b*256 + rf)*4 + kf)*512 + l*8 + e] = X[b][rf*16 + (l&15)][kf*32 + (l>>4)*8 + e]
__global__ __launch_bounds__(256) void cvt_frag_kernel(const float* __restrict__ s0,
                                                       const float* __restrict__ s1,
                                                       unsigned short* __restrict__ d0,
                                                       unsigned short* __restrict__ d1) {
  const float* src = blockIdx.y ? s1 : s0;
  unsigned short* dst = blockIdx.y ? d1 : d0;
  const int blk = blockIdx.x;          // b*256 + rf
  const int b = blk >> 8, rf = blk & 255;
  const int kf = threadIdx.x >> 6, l = threadIdx.x & 63;
  const int lr = l & 15, hg = l >> 4;
  const float* s = src + ((size_t)(b * 4096 + rf * 16 + lr) * DD + kf * 32 + hg * 8);
  bf16x8 r = pack8(s);
  *(bf16x8*)(dst + (((size_t)((b * 256 + rf) * 4 + kf)) << 9) + (l << 3)) = r;
}

// V fp32 [b][m][d] -> fragment-tiled transposed bf16:
// vt[((b*8 + djg)*128 + mt)*512 + l*8 + e] = V[b][mt*32 + (l>>4)*8 + e][djg*16 + (l&15)]
__global__ __launch_bounds__(256) void transpose_v_frag_kernel(const float* __restrict__ v,
                                                               unsigned short* __restrict__ vt) {
  __shared__ unsigned short t[64][72];   // [d_local][m_local]
  const int b = blockIdx.z, d0 = blockIdx.y * 64, m0 = blockIdx.x * 64;
  const int r = threadIdx.x >> 2, c4 = threadIdx.x & 3;
  const float* src = v + ((size_t)b * MM + m0 + r) * DD + d0 + c4 * 16;
  for (int j = 0; j < 4; ++j) {
    float4 x = *(const float4*)(src + j * 4);
    int dl = c4 * 16 + j * 4;
    t[dl + 0][r] = (unsigned short)f2bf(x.x);
    t[dl + 1][r] = (unsigned short)f2bf(x.y);
    t[dl + 2][r] = (unsigned short)f2bf(x.z);
    t[dl + 3][r] = (unsigned short)f2bf(x.w);
  }
  __syncthreads();
  const int s8 = threadIdx.x >> 5;          // 0..7 sub-tiles (16d x 32m)
  const int dfl = s8 & 3, mtl = s8 >> 2;
  const int t32 = threadIdx.x & 31;
  for (int ll = 0; ll < 2; ++ll) {
    const int l = t32 * 2 + ll;
    const int lr = l & 15, hg = l >> 4;
    bf16x8 val = *(bf16x8*)&t[dfl * 16 + lr][mtl * 32 + hg * 8];
    *(bf16x8*)(vt + (((size_t)((b * 8 + (d0 >> 4) + dfl) * 128 + (m0 >> 5) + mtl)) << 9) +
               (l << 3)) = val;
  }
}

// Sum NCH fragment-ordered f32 partials -> out[b][n][d]
__global__ __launch_bounds__(256) void reduce4_frag_kernel(const float* __restrict__ p,
                                                           float* __restrict__ out) {
  const size_t idx = (size_t)blockIdx.x * 256 + threadIdx.x;  // 524288 total
  f32x4 r = *(const f32x4*)(p + idx * 4);
  for (int c = 1; c < NCH; ++c) {
    f32x4 a = *(const f32x4*)(p + (size_t)c * OUT_ELEMS + idx * 4);
    r[0] += a[0]; r[1] += a[1]; r[2] += a[2]; r[3] += a[3];
  }
  const int l = (int)(idx & 63);
  const int djg = (int)((idx >> 6) & 7);
  const int nf = (int)((idx >> 9) & 255);
  const int bq = (int)(idx >> 17);
  const int lr = l & 15, hg = l >> 4;
  float* o = out + ((size_t)(bq * 4096 + nf * 16 + hg * 4) * DD + djg * 16 + lr);
  o[0] = r[0]; o[DD] = r[1]; o[2 * DD] = r[2]; o[3 * DD] = r[3];
}

// Raw barrier: LDS visibility only — global loads stay in flight (no vmcnt drain).
#define LGKM0_SBAR()                                        \
  do {                                                      \
    asm volatile("s_waitcnt lgkmcnt(0)" ::: "memory");      \
    __builtin_amdgcn_sched_barrier(0);                      \
    __builtin_amdgcn_s_barrier();                           \
  } while (0)

// Fused main kernel. XCD-pinned chunks; fragment-tiled operands (SGPR base + lane*16B).
// QK computed TRANSPOSED (mfma(Q,K) -> S[m][n]) so softmax lanes own 4 consecutive m:
// W written to LDS as 4x b64 instead of 16x u16. bf16 S-exchange (b64 both ways).
template <bool WS, bool PART>
__global__ __launch_bounds__(512, 4) void attn_fused(
    const float* __restrict__ k, const float* __restrict__ q, const float* __restrict__ v,
    const unsigned short* __restrict__ kbt, const unsigned short* __restrict__ qbt,
    const unsigned short* __restrict__ vtt, float* __restrict__ outp) {
  __shared__ alignas(8)  unsigned short s_pos[NB][8][64][4];   // 16 KB bf16 S^T exchange
  __shared__ alignas(16) unsigned short Wl[NB][BN][BM];        // 16 KB [b][n][m], m swizzled

  const int tid = threadIdx.x;
  const int wv = tid >> 6, l = tid & 63, lr = l & 15, hg = l >> 4;
  const int voff = l << 3;                  // lane offset in elems (16 B)
  const int wg = blockIdx.x;
  const int cid = wg & (NCH - 1);
  const int n0 = (wg >> 2) * BN;
  const int it0 = cid * (MM / BM / NCH);
  const int it1 = it0 + (MM / BM / NCH);

  const int bq = wv >> 1, h = wv & 1;          // (batch, m-half) for QK/PV phases
  const int h_s = wv >> 2, fi_s = (wv >> 1) & 1, fj_s = wv & 1;  // softmax slot

  // K fragments (register-cached): rows n0..n0+31 of batch bq, full D
  bf16x8 ka[2][4];
  {
    const unsigned short* kp = WS ? (kbt + rfl(((bq * 256 + (n0 >> 4)) * 4) << 9)) : nullptr;
    for (int fn = 0; fn < 2; ++fn)
      for (int kf = 0; kf < 4; ++kf) {
        if (WS) ka[fn][kf] = *(const bf16x8*)(kp + fn * 2048 + kf * 512 + voff);
        else    ka[fn][kf] = pack8(k + ((size_t)bq * NN + n0 + fn * 16 + lr) * DD +
                                   kf * 32 + hg * 8);
      }
  }

  f32x4 acc[2][4];
  for (int fi = 0; fi < 2; ++fi)
    for (int dj = 0; dj < 4; ++dj) acc[fi][dj] = (f32x4){0.f, 0.f, 0.f, 0.f};

  bf16x8 vf[4][2];   // V fragments, live across one barrier
  bf16x8 qf[2][4];   // Q fragments

  auto load_q = [&](int it) {
    if (WS) {
      const unsigned short* qp = qbt + rfl(((bq * 256 + it * 4 + h * 2) * 4) << 9);
      for (int fm = 0; fm < 2; ++fm)
        for (int kf = 0; kf < 4; ++kf)
          qf[fm][kf] = *(const bf16x8*)(qp + fm * 2048 + kf * 512 + voff);
    } else {
      const int m0 = it * BM;
      for (int fm = 0; fm < 2; ++fm)
        for (int kf = 0; kf < 4; ++kf)
          qf[fm][kf] = pack8(q + ((size_t)bq * MM + m0 + h * 32 + fm * 16 + lr) * DD +
                             kf * 32 + hg * 8);
    }
  };

  auto qk_mfma = [&]() {
    f32x4 s[2][2];   // [fm][fn], S^T: row=m, col=n
    for (int fm = 0; fm < 2; ++fm)
      for (int fn = 0; fn < 2; ++fn) s[fm][fn] = (f32x4){0.f, 0.f, 0.f, 0.f};
    __builtin_amdgcn_s_setprio(1);
    for (int kf = 0; kf < 4; ++kf)
      for (int fm = 0; fm < 2; ++fm)
        for (int fn = 0; fn < 2; ++fn)
          s[fm][fn] = __builtin_amdgcn_mfma_f32_16x16x32_bf16(qf[fm][kf], ka[fn][kf],
                                                              s[fm][fn], 0, 0, 0);
    __builtin_amdgcn_s_setprio(0);
    for (int fm = 0; fm < 2; ++fm)
      for (int fn = 0; fn < 2; ++fn) {
        short4 pk;
        pk.x = f2bf(s[fm][fn][0]); pk.y = f2bf(s[fm][fn][1]);
        pk.z = f2bf(s[fm][fn][2]); pk.w = f2bf(s[fm][fn][3]);
        *(short4*)&s_pos[bq][h * 4 + fm * 2 + fn][l][0] = pk;   // b64
      }
  };

  auto issue_v = [&](int it) {
    if (WS) {
      const unsigned short* vp = vtt + rfl((((bq * 8 + h * 4) * 128) + it * 2) << 9);
      for (int dj = 0; dj < 4; ++dj)
        for (int kf = 0; kf < 2; ++kf)
          vf[dj][kf] = *(const bf16x8*)(vp + dj * 65536 + kf * 512 + voff);
    } else {
      const int m0 = it * BM;
      for (int dj = 0; dj < 4; ++dj)
        for (int kf = 0; kf < 2; ++kf) {
          bf16x8 t;
          for (int e = 0; e < 8; ++e)
            t[e] = f2bf(v[((size_t)bq * MM + m0 + kf * 32 + hg * 8 + e) * DD +
                          h * 64 + dj * 16 + lr]);
          vf[dj][kf] = t;
        }
    }
  };

  auto do_sm = [&]() {
    // slot wv: m = h_s*32 + fi_s*16 + hg*4 + qq (4 consecutive), n = fj_s*16 + lr
    float sv[NB][4], w[NB][4];
    for (int bb = 0; bb < NB; ++bb) {
      short4 sp = *(short4*)&s_pos[bb][wv][l][0];
      sv[bb][0] = bf2f((unsigned short)sp.x); sv[bb][1] = bf2f((unsigned short)sp.y);
      sv[bb][2] = bf2f((unsigned short)sp.z); sv[bb][3] = bf2f((unsigned short)sp.w);
    }
    const float L2E = 1.4426950408889634f;
    for (int qq = 0; qq < 4; ++qq) {
      float e0 = fast_exp2(sv[0][qq] * L2E), e1 = fast_exp2(sv[1][qq] * L2E);
      float e2 = fast_exp2(sv[2][qq] * L2E), e3 = fast_exp2(sv[3][qq] * L2E);
      float inv = __builtin_amdgcn_rcpf((e0 + e1) + (e2 + e3)) * L2E;
      float f0 = fast_exp2(e0 * inv), f1 = fast_exp2(e1 * inv);
      float f2v = fast_exp2(e2 * inv), f3 = fast_exp2(e3 * inv);
      float inv2 = __builtin_amdgcn_rcpf((f0 + f1) + (f2v + f3));
      w[0][qq] = f0 * inv2; w[1][qq] = f1 * inv2;
      w[2][qq] = f2v * inv2; w[3][qq] = f3 * inv2;
    }
    const int n_loc = fj_s * 16 + lr;
    // m base = h_s*32 + fi_s*16 + hg*4; swizzle on 8-elem chunks: chunk ^ (n&7)
    const int mchunk = (h_s * 4 + fi_s * 2 + (hg >> 1)) ^ (n_loc & 7);
    const int moff = mchunk * 8 + (hg & 1) * 4;
    for (int bb = 0; bb < NB; ++bb) {
      short4 pk;
      pk.x = f2bf(w[bb][0]); pk.y = f2bf(w[bb][1]);
      pk.z = f2bf(w[bb][2]); pk.w = f2bf(w[bb][3]);
      *(short4*)&Wl[bb][n_loc][moff] = pk;   // b64, 4 consecutive m
    }
  };

  auto do_pv = [&]() {
    bf16x8 wf[2][2];
    for (int fi = 0; fi < 2; ++fi)
      for (int kf = 0; kf < 2; ++kf) {
        const int row = fi * 16 + lr, mo = kf * 32 + hg * 8;
        wf[fi][kf] = *(bf16x8*)&Wl[bq][row][mo ^ ((row & 7) << 3)];
      }
    __builtin_amdgcn_s_setprio(1);
    for (int kf = 0; kf < 2; ++kf)
      for (int fi = 0; fi < 2; ++fi)
        for (int dj = 0; dj < 4; ++dj)
          acc[fi][dj] = __builtin_amdgcn_mfma_f32_16x16x32_bf16(wf[fi][kf], vf[dj][kf],
                                                                acc[fi][dj], 0, 0, 0);
    __builtin_amdgcn_s_setprio(0);
  };

  // ---- rotated pipeline, 2 raw barriers per iteration ----
  load_q(it0);
  qk_mfma();
  LGKM0_SBAR();
  for (int t = it0; t < it1; ++t) {
    issue_v(t);              // V loads in flight across the barrier, land before PV
    do_sm();
    LGKM0_SBAR();
    do_pv();                 // vf dies here; load_q after keeps peak liveness low
    if (t + 1 < it1) {
      load_q(t + 1);
      qk_mfma();
    }
    LGKM0_SBAR();
  }

  // ---- epilogue ----
  if (PART) {
    float* dst = outp + (size_t)cid * OUT_ELEMS +
                 rfl((((bq * 256 + (n0 >> 4)) * 8 + h * 4)) << 8);
    for (int fi = 0; fi < 2; ++fi)
      for (int dj = 0; dj < 4; ++dj)
        *(f32x4*)(dst + fi * 2048 + dj * 256 + (l << 2)) = acc[fi][dj];
  } else {
    float* dst = outp;
    for (int fi = 0; fi < 2; ++fi)
      for (int dj = 0; dj < 4; ++dj)
        for (int qq = 0; qq < 4; ++qq)
          atomicAdd(dst + ((size_t)bq * NN + n0 + fi * 16 + hg * 4 + qq) * DD +
                        h * 64 + dj * 16 + lr,
                    acc[fi][dj][qq]);
  }
}

extern "C" void kernel_launch(void* const* d_in, const int* in_sizes, int n_in,
                              void* d_out, int out_size, void* d_ws, size_t ws_size,
                              hipStream_t stream) {
  (void)in_sizes; (void)n_in; (void)out_size;
  const float* k = (const float*)d_in[0];
  const float* q = (const float*)d_in[1];
  const float* v = (const float*)d_in[2];
  float* out = (float*)d_out;

  const size_t elems = (size_t)NB * MM * DD;                    // 2M per tensor
  const size_t need_bf = 3 * elems * sizeof(unsigned short);    // 12 MB
  const size_t need_full = need_bf + NCH * OUT_ELEMS * sizeof(float);  // 44 MB
  const bool use_ws = (d_ws != nullptr) && (ws_size >= need_bf);
  const bool use_part = (d_ws != nullptr) && (ws_size >= need_full);

  if (use_ws) {
    unsigned short* kbt = (unsigned short*)d_ws;
    unsigned short* qbt = kbt + elems;
    unsigned short* vtt = qbt + elems;
    cvt_frag_kernel<<<dim3(NB * 256, 2), 256, 0, stream>>>(k, q, kbt, qbt);
    transpose_v_frag_kernel<<<dim3(MM / 64, DD / 64, NB), 256, 0, stream>>>(v, vtt);
    if (use_part) {
      float* partials = (float*)((char*)d_ws + need_bf);
      attn_fused<true, true><<<dim3(NN / BN * NCH), 512, 0, stream>>>(k, q, v, kbt, qbt, vtt,
                                                                      partials);
      reduce4_frag_kernel<<<2048, 256, 0, stream>>>(partials, out);
    } else {
      zero_out_kernel<<<(NB * NN * DD) / 4 / 256, 256, 0, stream>>>((float4*)out);
      attn_fused<true, false><<<dim3(NN / BN * NCH), 512, 0, stream>>>(k, q, v, kbt, qbt, vtt,
                                                                       out);
    }
  } else {
    zero_out_kernel<<<(NB * NN * DD) / 4 / 256, 256, 0, stream>>>((float4*)out);
    attn_fused<false, false><<<dim3(NN / BN * NCH), 512, 0, stream>>>(k, q, v, nullptr,
                                                                      nullptr, nullptr, out);
  }
}